// Round 12
// baseline (349.781 us; speedup 1.0000x reference)
//
#include <hip/hip_runtime.h>
#include <hip/hip_bf16.h>

#define N_PTS 65536
#define BATCH 2
#define KNN   16
#define NBLK_V2 2048
#define NBLK_V1 512

typedef float float4n __attribute__((ext_vector_type(4)));

__device__ __forceinline__ int tri(int i, int j) { // i<=j, 7x7 upper triangle
    return i * 7 - (i * (i - 1)) / 2 + (j - i);
}

// ==== v2 stats: one k-quad per thread; 2048 blocks ====
__global__ __launch_bounds__(256) void k_stats4(const float* __restrict__ coords,
                                                const int* __restrict__ knn,
                                                const float* __restrict__ dist,
                                                float* __restrict__ partials) {
    int gid = blockIdx.x * 256 + threadIdx.x;   // B*N*4 threads
    int q  = gid & 3;
    int pp = gid >> 2;                           // b*N + n
    int b  = pp >> 16;
    const float* cp = coords + (size_t)pp * 3;
    float cx = cp[0], cy = cp[1], cz = cp[2];
    const float* cb = coords + (size_t)b * (N_PTS * 3);

    int4   ia = *(const int4*)  (knn  + ((size_t)pp << 4) + (q << 2));
    float4 da = *(const float4*)(dist + ((size_t)pp << 4) + (q << 2));
    int   idx[4] = {ia.x, ia.y, ia.z, ia.w};
    float dd[4]  = {da.x, da.y, da.z, da.w};

    float s[35];
#pragma unroll
    for (int i = 0; i < 35; i++) s[i] = 0.f;

#pragma unroll
    for (int k = 0; k < 4; k++) {
        const float* qq = cb + (size_t)idx[k] * 3;
        float v[7];
        v[0] = cx; v[1] = cy; v[2] = cz;
        v[3] = qq[0]; v[4] = qq[1]; v[5] = qq[2];
        v[6] = dd[k];
        int t = 7;
#pragma unroll
        for (int i = 0; i < 7; i++) {
            s[i] += v[i];
#pragma unroll
            for (int j = i; j < 7; j++) { s[t] += v[i] * v[j]; t++; }
        }
    }

    __shared__ float red[4][35];
    int lane = threadIdx.x & 63;
    int wid  = threadIdx.x >> 6;
#pragma unroll
    for (int i = 0; i < 35; i++) {
        float v = s[i];
#pragma unroll
        for (int off = 32; off; off >>= 1) v += __shfl_xor(v, off);
        if (lane == 0) red[wid][i] = v;
    }
    __syncthreads();
    if (threadIdx.x < 35) {
        int i = threadIdx.x;
        partials[i * NBLK_V2 + blockIdx.x] =
            (red[0][i] + red[1][i]) + (red[2][i] + red[3][i]);
    }
}

// ==== v2 prep: 256-thread parallel partials reduce + BN fold ====
__global__ __launch_bounds__(256) void k_prep256(const float* __restrict__ W,
                                                 const float* __restrict__ bias,
                                                 const float* __restrict__ gamma,
                                                 const float* __restrict__ beta,
                                                 const float* __restrict__ partials,
                                                 float* __restrict__ w8) {
    __shared__ float red[4][35];
    __shared__ float sst[35];
    int t = threadIdx.x;
    float acc[35];
    const float* p0 = partials + t * 8;
#pragma unroll
    for (int i = 0; i < 35; i++) {
        const float* p = p0 + i * NBLK_V2;
        float4 a = *(const float4*)p;
        float4 c = *(const float4*)(p + 4);
        acc[i] = ((a.x + a.y) + (a.z + a.w)) + ((c.x + c.y) + (c.z + c.w));
    }
    int lane = t & 63, wid = t >> 6;
#pragma unroll
    for (int i = 0; i < 35; i++) {
        float v = acc[i];
#pragma unroll
        for (int off = 32; off; off >>= 1) v += __shfl_xor(v, off);
        if (lane == 0) red[wid][i] = v;
    }
    __syncthreads();
    if (t < 35) sst[t] = (red[0][t] + red[1][t]) + (red[2][t] + red[3][t]);
    __syncthreads();

    if (t >= 64) return;
    int o = t; // 0..63
    const float invM = 1.0f / (float)((size_t)BATCH * N_PTS * KNN);
    float m[7];
#pragma unroll
    for (int j = 0; j < 7; j++) m[j] = sst[j] * invM;
    const float* Wo = W + o * 10;
    float wv[7];
    wv[0] = Wo[0] + Wo[6]; wv[1] = Wo[1] + Wo[7]; wv[2] = Wo[2] + Wo[8];
    wv[3] = Wo[3] - Wo[6]; wv[4] = Wo[4] - Wo[7]; wv[5] = Wo[5] - Wo[8];
    wv[6] = Wo[9];
    float mean = bias[o];
#pragma unroll
    for (int j = 0; j < 7; j++) mean += wv[j] * m[j];
    float var = 0.f;
#pragma unroll
    for (int i = 0; i < 7; i++) {
#pragma unroll
        for (int j = 0; j < 7; j++) {
            int a = i < j ? i : j, c = i < j ? j : i;
            float cov = sst[7 + tri(a, c)] * invM - m[i] * m[j];
            var += wv[i] * wv[j] * cov;
        }
    }
    float s = gamma[o] * rsqrtf(var + 1e-6f);
    float sh = beta[o] - mean * s;
#pragma unroll
    for (int j = 0; j < 7; j++) w8[o * 8 + j] = s * wv[j];
    w8[o * 8 + 7] = s * bias[o] + sh;
}

// ==== fallback stats (512 blocks) ====
__global__ __launch_bounds__(256) void k_stats_fb(const float* __restrict__ coords,
                                                  const int* __restrict__ knn,
                                                  const float* __restrict__ dist,
                                                  float* __restrict__ stats_atomic,
                                                  float* __restrict__ partials,
                                                  int use_part) {
    int gid = blockIdx.x * 256 + threadIdx.x;
    int b = gid >> 16;
    const float* cp = coords + (size_t)gid * 3;
    float cx = cp[0], cy = cp[1], cz = cp[2];
    const float* cb = coords + (size_t)b * (N_PTS * 3);
    const int* ip = knn + ((size_t)gid << 4);
    const float* dp = dist + ((size_t)gid << 4);

    float s[35];
#pragma unroll
    for (int i = 0; i < 35; i++) s[i] = 0.f;
    for (int k = 0; k < KNN; k++) {
        int idx = ip[k];
        const float* q = cb + (size_t)idx * 3;
        float v[7];
        v[0] = cx; v[1] = cy; v[2] = cz;
        v[3] = q[0]; v[4] = q[1]; v[5] = q[2];
        v[6] = dp[k];
        int t = 7;
#pragma unroll
        for (int i = 0; i < 7; i++) {
            s[i] += v[i];
#pragma unroll
            for (int j = i; j < 7; j++) { s[t] += v[i] * v[j]; t++; }
        }
    }
    __shared__ float red[4][35];
    int lane = threadIdx.x & 63;
    int wid  = threadIdx.x >> 6;
#pragma unroll
    for (int i = 0; i < 35; i++) {
        float v = s[i];
#pragma unroll
        for (int off = 32; off; off >>= 1) v += __shfl_xor(v, off);
        if (lane == 0) red[wid][i] = v;
    }
    __syncthreads();
    if (threadIdx.x < 35) {
        int i = threadIdx.x;
        float v = (red[0][i] + red[1][i]) + (red[2][i] + red[3][i]);
        if (use_part) partials[i * NBLK_V1 + blockIdx.x] = v;
        else          atomicAdd(&stats_atomic[i], v);
    }
}

// ==== fallback prep (64 threads) ====
__global__ __launch_bounds__(64) void k_prep_fb(const float* __restrict__ W,
                                                const float* __restrict__ bias,
                                                const float* __restrict__ gamma,
                                                const float* __restrict__ beta,
                                                const float* __restrict__ stats_atomic,
                                                const float* __restrict__ partials,
                                                int use_part,
                                                float* __restrict__ w8) {
    __shared__ float sst[35];
    int t = threadIdx.x;
    if (t < 35) {
        if (use_part) {
            const float* p = partials + t * NBLK_V1;
            float a0 = 0.f, a1 = 0.f, a2 = 0.f, a3 = 0.f;
            for (int j = 0; j < NBLK_V1; j += 4) {
                a0 += p[j]; a1 += p[j + 1]; a2 += p[j + 2]; a3 += p[j + 3];
            }
            sst[t] = (a0 + a1) + (a2 + a3);
        } else {
            sst[t] = stats_atomic[t];
        }
    }
    __syncthreads();
    int o = t;
    const float invM = 1.0f / (float)((size_t)BATCH * N_PTS * KNN);
    float m[7];
#pragma unroll
    for (int j = 0; j < 7; j++) m[j] = sst[j] * invM;
    const float* Wo = W + o * 10;
    float wv[7];
    wv[0] = Wo[0] + Wo[6]; wv[1] = Wo[1] + Wo[7]; wv[2] = Wo[2] + Wo[8];
    wv[3] = Wo[3] - Wo[6]; wv[4] = Wo[4] - Wo[7]; wv[5] = Wo[5] - Wo[8];
    wv[6] = Wo[9];
    float mean = bias[o];
#pragma unroll
    for (int j = 0; j < 7; j++) mean += wv[j] * m[j];
    float var = 0.f;
#pragma unroll
    for (int i = 0; i < 7; i++) {
#pragma unroll
        for (int j = 0; j < 7; j++) {
            int a = i < j ? i : j, c = i < j ? j : i;
            float cov = sst[7 + tri(a, c)] * invM - m[i] * m[j];
            var += wv[i] * wv[j] * cov;
        }
    }
    float s = gamma[o] * rsqrtf(var + 1e-6f);
    float sh = beta[o] - mean * s;
#pragma unroll
    for (int j = 0; j < 7; j++) w8[o * 8 + j] = s * wv[j];
    w8[o * 8 + 7] = s * bias[o] + sh;
}

// ==== Pass 2: x channels; 4 threads/point; unit-stride THROUGH-L2 stores ====
// (single variable vs r11: NT removed here so L2 aggregates the 4MiB-strided
//  1KB channel bursts into sequential HBM streams; k_feat keeps NT)
__global__ __launch_bounds__(256) void k_x(const float* __restrict__ coords,
                                           const int* __restrict__ knn,
                                           const float* __restrict__ dist,
                                           const float* __restrict__ w8g,
                                           float* __restrict__ out) {
    __shared__ float w8[512];
    for (int i = threadIdx.x; i < 512; i += 256) w8[i] = w8g[i];
    __syncthreads();

    int gid = blockIdx.x * 256 + threadIdx.x;   // B*N*4 threads
    int q  = gid & 3;
    int pp = gid >> 2;
    int b = pp >> 16;
    int n = pp & 0xFFFF;

    const float* cp = coords + (size_t)pp * 3;
    float cx = cp[0], cy = cp[1], cz = cp[2];
    const float* cb = coords + (size_t)b * (N_PTS * 3);

    int4   ia = *(const int4*)  (knn  + ((size_t)pp << 4) + (q << 2));
    float4 da = *(const float4*)(dist + ((size_t)pp << 4) + (q << 2));
    int   idx[4] = {ia.x, ia.y, ia.z, ia.w};
    float dd[4]  = {da.x, da.y, da.z, da.w};
    float nx[4], ny[4], nz[4];
#pragma unroll
    for (int k = 0; k < 4; k++) {
        const float* qq = cb + (size_t)idx[k] * 3;
        nx[k] = qq[0]; ny[k] = qq[1]; nz[k] = qq[2];
    }

    size_t base = ((size_t)b * 128) * (N_PTS * KNN) + (size_t)n * KNN + (q << 2);
#pragma unroll 4
    for (int c = 0; c < 64; c++) {
        float4 wa = *reinterpret_cast<const float4*>(&w8[c << 3]);
        float4 wb = *reinterpret_cast<const float4*>(&w8[(c << 3) + 4]);
        float s0 = fmaf(cx, wa.x, fmaf(cy, wa.y, fmaf(cz, wa.z, wb.w)));
        float x[4];
#pragma unroll
        for (int k = 0; k < 4; k++) {
            float v = fmaf(dd[k], wb.z, fmaf(nz[k], wb.y, fmaf(ny[k], wb.x, fmaf(nx[k], wa.w, s0))));
            x[k] = fmaxf(v, 0.f);
        }
        *reinterpret_cast<float4*>(out + base + (size_t)c * (N_PTS * KNN)) =
            make_float4(x[0], x[1], x[2], x[3]);
    }
}

// ==== Pass 3: feature broadcast; unit-stride NT stores ====
__global__ __launch_bounds__(256) void k_feat(const float* __restrict__ feat,
                                              float* __restrict__ out) {
    int gid = blockIdx.x * 256 + threadIdx.x;  // B*64*N*4 threads
    int q4 = gid & 3;
    int r  = gid >> 2;
    float v = feat[r];
    int b = r >> 22;
    int f = (r >> 16) & 63;
    int n = r & 0xFFFF;
    size_t base = (((size_t)b * 128 + 64 + f) * N_PTS + n) * KNN + (q4 << 2);
    float4n vv = {v, v, v, v};
    __builtin_nontemporal_store(vv, reinterpret_cast<float4n*>(out + base));
}

extern "C" void kernel_launch(void* const* d_in, const int* in_sizes, int n_in,
                              void* d_out, int out_size, void* d_ws, size_t ws_size,
                              hipStream_t stream) {
    const float* coords   = (const float*)d_in[0];
    const float* features = (const float*)d_in[1];
    const int*   knn      = (const int*)d_in[2];
    const float* dist     = (const float*)d_in[3];
    const float* W        = (const float*)d_in[4];
    const float* bias     = (const float*)d_in[5];
    const float* gamma    = (const float*)d_in[6];
    const float* beta     = (const float*)d_in[7];
    float* out            = (float*)d_out;

    // ws layout: stats[64] | w8[512] | partials[...]
    float* stats    = (float*)d_ws;
    float* w8       = stats + 64;
    float* partials = w8 + 512;
    size_t need2 = (64 + 512 + 35 * NBLK_V2) * sizeof(float);
    size_t need1 = (64 + 512 + 35 * NBLK_V1) * sizeof(float);

    if (ws_size >= need2) {
        k_stats4<<<NBLK_V2, 256, 0, stream>>>(coords, knn, dist, partials);
        k_prep256<<<1, 256, 0, stream>>>(W, bias, gamma, beta, partials, w8);
    } else {
        int use_part = (ws_size >= need1) ? 1 : 0;
        if (!use_part)
            (void)hipMemsetAsync(d_ws, 0, 64 * sizeof(float), stream);
        k_stats_fb<<<NBLK_V1, 256, 0, stream>>>(coords, knn, dist, stats, partials, use_part);
        k_prep_fb<<<1, 64, 0, stream>>>(W, bias, gamma, beta, stats, partials, use_part, w8);
    }
    k_x<<<2048, 256, 0, stream>>>(coords, knn, dist, w8, out);
    k_feat<<<131072, 256, 0, stream>>>(features, out);
}

// Round 13
// 232.131 us; speedup vs baseline: 1.5068x; 1.5068x over previous
//
#include <hip/hip_runtime.h>
#include <hip/hip_bf16.h>

#define N_PTS 65536
#define BATCH 2
#define KNN   16
#define NBLK_S2 2048
#define NBLK_V1 512

typedef float float4n __attribute__((ext_vector_type(4)));

__device__ __forceinline__ int tri(int i, int j) { // i<=j, 7x7 upper triangle
    return i * 7 - (i * (i - 1)) / 2 + (j - i);
}

// ==== Fused: blocks [0,2048) = LEAN stats (factored moments, <=64 VGPR);
//      blocks [2048,...) = feature broadcast (unit-stride NT, r11-proven) ====
__global__ __launch_bounds__(256) void k_featstats(const float* __restrict__ feat,
                                                   float* __restrict__ out,
                                                   const float* __restrict__ coords,
                                                   const int* __restrict__ knn,
                                                   const float* __restrict__ dist,
                                                   float* __restrict__ partials) {
    int bid = blockIdx.x;
    if (bid < NBLK_S2) {
        // ---- lean stats role: one k-quad per thread, 14 factored accumulators ----
        int gid = bid * 256 + threadIdx.x;   // B*N*4 = 524288 threads
        int q  = gid & 3;
        int pp = gid >> 2;                   // b*N + n
        int b  = pp >> 16;
        const float* cp = coords + (size_t)pp * 3;
        float cx = cp[0], cy = cp[1], cz = cp[2];
        const float* cb = coords + (size_t)b * (N_PTS * 3);

        int4   ia = *(const int4*)  (knn  + ((size_t)pp << 4) + (q << 2));
        float4 da = *(const float4*)(dist + ((size_t)pp << 4) + (q << 2));
        int   idx[4] = {ia.x, ia.y, ia.z, ia.w};
        float dd[4]  = {da.x, da.y, da.z, da.w};

        float Gx = 0.f, Gy = 0.f, Gz = 0.f, D1 = 0.f, D2 = 0.f;
        float Sxx = 0.f, Sxy = 0.f, Sxz = 0.f, Syy = 0.f, Syz = 0.f, Szz = 0.f;
        float NDx = 0.f, NDy = 0.f, NDz = 0.f;
#pragma unroll
        for (int k = 0; k < 4; k++) {
            const float* qq = cb + (size_t)idx[k] * 3;
            float nx = qq[0], ny = qq[1], nz = qq[2], d = dd[k];
            Gx += nx; Gy += ny; Gz += nz; D1 += d; D2 += d * d;
            Sxx += nx * nx; Sxy += nx * ny; Sxz += nx * nz;
            Syy += ny * ny; Syz += ny * nz; Szz += nz * nz;
            NDx += nx * d; NDy += ny * d; NDz += nz * d;
        }

        __shared__ float red[4][35];
        int lane = threadIdx.x & 63, wid = threadIdx.x >> 6;
        int slot = 0;
        // expand the 35 moment terms one at a time (transient; keeps VGPR low),
        // order matches stats[0..6], stats[7+tri(i,j)]
#define RED1(expr) { float v_ = (expr); \
        v_ += __shfl_xor(v_, 32); v_ += __shfl_xor(v_, 16); \
        v_ += __shfl_xor(v_, 8);  v_ += __shfl_xor(v_, 4);  \
        v_ += __shfl_xor(v_, 2);  v_ += __shfl_xor(v_, 1);  \
        if (lane == 0) red[wid][slot] = v_; slot++; }
        RED1(4.f*cx) RED1(4.f*cy) RED1(4.f*cz) RED1(Gx) RED1(Gy) RED1(Gz) RED1(D1)
        RED1(4.f*cx*cx) RED1(4.f*cx*cy) RED1(4.f*cx*cz)
        RED1(cx*Gx) RED1(cx*Gy) RED1(cx*Gz) RED1(cx*D1)
        RED1(4.f*cy*cy) RED1(4.f*cy*cz)
        RED1(cy*Gx) RED1(cy*Gy) RED1(cy*Gz) RED1(cy*D1)
        RED1(4.f*cz*cz)
        RED1(cz*Gx) RED1(cz*Gy) RED1(cz*Gz) RED1(cz*D1)
        RED1(Sxx) RED1(Sxy) RED1(Sxz) RED1(NDx)
        RED1(Syy) RED1(Syz) RED1(NDy)
        RED1(Szz) RED1(NDz)
        RED1(D2)
#undef RED1
        __syncthreads();
        if (threadIdx.x < 35) {
            int i = threadIdx.x;
            partials[i * NBLK_S2 + bid] =
                (red[0][i] + red[1][i]) + (red[2][i] + red[3][i]);
        }
    } else {
        // ---- feat-broadcast role (r11-proven: ~7 TB/s) ----
        int gid = (bid - NBLK_S2) * 256 + threadIdx.x;  // B*64*N*4 threads
        int q4 = gid & 3;
        int r  = gid >> 2;
        float v = feat[r];
        int b = r >> 22;
        int f = (r >> 16) & 63;
        int n = r & 0xFFFF;
        size_t base = (((size_t)b * 128 + 64 + f) * N_PTS + n) * KNN + (q4 << 2);
        float4n vv = {v, v, v, v};
        __builtin_nontemporal_store(vv, reinterpret_cast<float4n*>(out + base));
    }
}

// ==== prep: 256-thread parallel partials reduce + BN fold ====
__global__ __launch_bounds__(256) void k_prep256(const float* __restrict__ W,
                                                 const float* __restrict__ bias,
                                                 const float* __restrict__ gamma,
                                                 const float* __restrict__ beta,
                                                 const float* __restrict__ partials,
                                                 float* __restrict__ w8) {
    __shared__ float red[4][35];
    __shared__ float sst[35];
    int t = threadIdx.x;
    float acc[35];
    const float* p0 = partials + t * 8;
#pragma unroll
    for (int i = 0; i < 35; i++) {
        const float* p = p0 + i * NBLK_S2;
        float4 a = *(const float4*)p;
        float4 c = *(const float4*)(p + 4);
        acc[i] = ((a.x + a.y) + (a.z + a.w)) + ((c.x + c.y) + (c.z + c.w));
    }
    int lane = t & 63, wid = t >> 6;
#pragma unroll
    for (int i = 0; i < 35; i++) {
        float v = acc[i];
#pragma unroll
        for (int off = 32; off; off >>= 1) v += __shfl_xor(v, off);
        if (lane == 0) red[wid][i] = v;
    }
    __syncthreads();
    if (t < 35) sst[t] = (red[0][t] + red[1][t]) + (red[2][t] + red[3][t]);
    __syncthreads();

    if (t >= 64) return;
    int o = t; // 0..63
    const float invM = 1.0f / (float)((size_t)BATCH * N_PTS * KNN);
    float m[7];
#pragma unroll
    for (int j = 0; j < 7; j++) m[j] = sst[j] * invM;
    const float* Wo = W + o * 10;
    float wv[7];
    wv[0] = Wo[0] + Wo[6]; wv[1] = Wo[1] + Wo[7]; wv[2] = Wo[2] + Wo[8];
    wv[3] = Wo[3] - Wo[6]; wv[4] = Wo[4] - Wo[7]; wv[5] = Wo[5] - Wo[8];
    wv[6] = Wo[9];
    float mean = bias[o];
#pragma unroll
    for (int j = 0; j < 7; j++) mean += wv[j] * m[j];
    float var = 0.f;
#pragma unroll
    for (int i = 0; i < 7; i++) {
#pragma unroll
        for (int j = 0; j < 7; j++) {
            int a = i < j ? i : j, c = i < j ? j : i;
            float cov = sst[7 + tri(a, c)] * invM - m[i] * m[j];
            var += wv[i] * wv[j] * cov;
        }
    }
    float s = gamma[o] * rsqrtf(var + 1e-6f);
    float sh = beta[o] - mean * s;
#pragma unroll
    for (int j = 0; j < 7; j++) w8[o * 8 + j] = s * wv[j];
    w8[o * 8 + 7] = s * bias[o] + sh;
}

// ==== fallback stats (512 blocks, r9-proven) ====
__global__ __launch_bounds__(256) void k_stats_fb(const float* __restrict__ coords,
                                                  const int* __restrict__ knn,
                                                  const float* __restrict__ dist,
                                                  float* __restrict__ stats_atomic,
                                                  float* __restrict__ partials,
                                                  int use_part) {
    int gid = blockIdx.x * 256 + threadIdx.x;
    int b = gid >> 16;
    const float* cp = coords + (size_t)gid * 3;
    float cx = cp[0], cy = cp[1], cz = cp[2];
    const float* cb = coords + (size_t)b * (N_PTS * 3);
    const int* ip = knn + ((size_t)gid << 4);
    const float* dp = dist + ((size_t)gid << 4);

    float s[35];
#pragma unroll
    for (int i = 0; i < 35; i++) s[i] = 0.f;
    for (int k = 0; k < KNN; k++) {
        int idx = ip[k];
        const float* q = cb + (size_t)idx * 3;
        float v[7];
        v[0] = cx; v[1] = cy; v[2] = cz;
        v[3] = q[0]; v[4] = q[1]; v[5] = q[2];
        v[6] = dp[k];
        int t = 7;
#pragma unroll
        for (int i = 0; i < 7; i++) {
            s[i] += v[i];
#pragma unroll
            for (int j = i; j < 7; j++) { s[t] += v[i] * v[j]; t++; }
        }
    }
    __shared__ float red[4][35];
    int lane = threadIdx.x & 63;
    int wid  = threadIdx.x >> 6;
#pragma unroll
    for (int i = 0; i < 35; i++) {
        float v = s[i];
#pragma unroll
        for (int off = 32; off; off >>= 1) v += __shfl_xor(v, off);
        if (lane == 0) red[wid][i] = v;
    }
    __syncthreads();
    if (threadIdx.x < 35) {
        int i = threadIdx.x;
        float v = (red[0][i] + red[1][i]) + (red[2][i] + red[3][i]);
        if (use_part) partials[i * NBLK_V1 + blockIdx.x] = v;
        else          atomicAdd(&stats_atomic[i], v);
    }
}

// ==== fallback prep (64 threads, r9-proven) ====
__global__ __launch_bounds__(64) void k_prep_fb(const float* __restrict__ W,
                                                const float* __restrict__ bias,
                                                const float* __restrict__ gamma,
                                                const float* __restrict__ beta,
                                                const float* __restrict__ stats_atomic,
                                                const float* __restrict__ partials,
                                                int use_part,
                                                float* __restrict__ w8) {
    __shared__ float sst[35];
    int t = threadIdx.x;
    if (t < 35) {
        if (use_part) {
            const float* p = partials + t * NBLK_V1;
            float a0 = 0.f, a1 = 0.f, a2 = 0.f, a3 = 0.f;
            for (int j = 0; j < NBLK_V1; j += 4) {
                a0 += p[j]; a1 += p[j + 1]; a2 += p[j + 2]; a3 += p[j + 3];
            }
            sst[t] = (a0 + a1) + (a2 + a3);
        } else {
            sst[t] = stats_atomic[t];
        }
    }
    __syncthreads();
    int o = t;
    const float invM = 1.0f / (float)((size_t)BATCH * N_PTS * KNN);
    float m[7];
#pragma unroll
    for (int j = 0; j < 7; j++) m[j] = sst[j] * invM;
    const float* Wo = W + o * 10;
    float wv[7];
    wv[0] = Wo[0] + Wo[6]; wv[1] = Wo[1] + Wo[7]; wv[2] = Wo[2] + Wo[8];
    wv[3] = Wo[3] - Wo[6]; wv[4] = Wo[4] - Wo[7]; wv[5] = Wo[5] - Wo[8];
    wv[6] = Wo[9];
    float mean = bias[o];
#pragma unroll
    for (int j = 0; j < 7; j++) mean += wv[j] * m[j];
    float var = 0.f;
#pragma unroll
    for (int i = 0; i < 7; i++) {
#pragma unroll
        for (int j = 0; j < 7; j++) {
            int a = i < j ? i : j, c = i < j ? j : i;
            float cov = sst[7 + tri(a, c)] * invM - m[i] * m[j];
            var += wv[i] * wv[j] * cov;
        }
    }
    float s = gamma[o] * rsqrtf(var + 1e-6f);
    float sh = beta[o] - mean * s;
#pragma unroll
    for (int j = 0; j < 7; j++) w8[o * 8 + j] = s * wv[j];
    w8[o * 8 + 7] = s * bias[o] + sh;
}

// ==== fallback standalone feat broadcast ====
__global__ __launch_bounds__(256) void k_feat(const float* __restrict__ feat,
                                              float* __restrict__ out) {
    int gid = blockIdx.x * 256 + threadIdx.x;
    int q4 = gid & 3;
    int r  = gid >> 2;
    float v = feat[r];
    int b = r >> 22;
    int f = (r >> 16) & 63;
    int n = r & 0xFFFF;
    size_t base = (((size_t)b * 128 + 64 + f) * N_PTS + n) * KNN + (q4 << 2);
    float4n vv = {v, v, v, v};
    __builtin_nontemporal_store(vv, reinterpret_cast<float4n*>(out + base));
}

// ==== Pass 2: x channels; 4 threads/point; unit-stride NT stores (r11-proven) ====
__global__ __launch_bounds__(256) void k_x(const float* __restrict__ coords,
                                           const int* __restrict__ knn,
                                           const float* __restrict__ dist,
                                           const float* __restrict__ w8g,
                                           float* __restrict__ out) {
    __shared__ float w8[512];
    for (int i = threadIdx.x; i < 512; i += 256) w8[i] = w8g[i];
    __syncthreads();

    int gid = blockIdx.x * 256 + threadIdx.x;   // B*N*4 threads
    int q  = gid & 3;
    int pp = gid >> 2;
    int b = pp >> 16;
    int n = pp & 0xFFFF;

    const float* cp = coords + (size_t)pp * 3;
    float cx = cp[0], cy = cp[1], cz = cp[2];
    const float* cb = coords + (size_t)b * (N_PTS * 3);

    int4   ia = *(const int4*)  (knn  + ((size_t)pp << 4) + (q << 2));
    float4 da = *(const float4*)(dist + ((size_t)pp << 4) + (q << 2));
    int   idx[4] = {ia.x, ia.y, ia.z, ia.w};
    float dd[4]  = {da.x, da.y, da.z, da.w};
    float nx[4], ny[4], nz[4];
#pragma unroll
    for (int k = 0; k < 4; k++) {
        const float* qq = cb + (size_t)idx[k] * 3;
        nx[k] = qq[0]; ny[k] = qq[1]; nz[k] = qq[2];
    }

    size_t base = ((size_t)b * 128) * (N_PTS * KNN) + (size_t)n * KNN + (q << 2);
#pragma unroll 4
    for (int c = 0; c < 64; c++) {
        float4 wa = *reinterpret_cast<const float4*>(&w8[c << 3]);
        float4 wb = *reinterpret_cast<const float4*>(&w8[(c << 3) + 4]);
        float s0 = fmaf(cx, wa.x, fmaf(cy, wa.y, fmaf(cz, wa.z, wb.w)));
        float x[4];
#pragma unroll
        for (int k = 0; k < 4; k++) {
            float v = fmaf(dd[k], wb.z, fmaf(nz[k], wb.y, fmaf(ny[k], wb.x, fmaf(nx[k], wa.w, s0))));
            x[k] = fmaxf(v, 0.f);
        }
        float4n v0 = {x[0], x[1], x[2], x[3]};
        __builtin_nontemporal_store(v0,
            reinterpret_cast<float4n*>(out + base + (size_t)c * (N_PTS * KNN)));
    }
}

extern "C" void kernel_launch(void* const* d_in, const int* in_sizes, int n_in,
                              void* d_out, int out_size, void* d_ws, size_t ws_size,
                              hipStream_t stream) {
    const float* coords   = (const float*)d_in[0];
    const float* features = (const float*)d_in[1];
    const int*   knn      = (const int*)d_in[2];
    const float* dist     = (const float*)d_in[3];
    const float* W        = (const float*)d_in[4];
    const float* bias     = (const float*)d_in[5];
    const float* gamma    = (const float*)d_in[6];
    const float* beta     = (const float*)d_in[7];
    float* out            = (float*)d_out;

    // ws layout: stats[64] | w8[512] | partials[...]
    float* stats    = (float*)d_ws;
    float* w8       = stats + 64;
    float* partials = w8 + 512;
    size_t need2 = (64 + 512 + 35 * NBLK_S2) * sizeof(float);
    size_t need1 = (64 + 512 + 35 * NBLK_V1) * sizeof(float);

    if (ws_size >= need2) {
        // stats hidden under the write-bound feat broadcast; lean role keeps VGPR<=64
        k_featstats<<<NBLK_S2 + 131072, 256, 0, stream>>>(features, out, coords, knn, dist,
                                                          partials);
        k_prep256<<<1, 256, 0, stream>>>(W, bias, gamma, beta, partials, w8);
    } else {
        int use_part = (ws_size >= need1) ? 1 : 0;
        if (!use_part)
            (void)hipMemsetAsync(d_ws, 0, 64 * sizeof(float), stream);
        k_stats_fb<<<NBLK_V1, 256, 0, stream>>>(coords, knn, dist, stats, partials, use_part);
        k_prep_fb<<<1, 64, 0, stream>>>(W, bias, gamma, beta, stats, partials, use_part, w8);
        k_feat<<<131072, 256, 0, stream>>>(features, out);
    }
    k_x<<<2048, 256, 0, stream>>>(coords, knn, dist, w8, out);
}

// Round 14
// 216.808 us; speedup vs baseline: 1.6133x; 1.0707x over previous
//
#include <hip/hip_runtime.h>
#include <hip/hip_bf16.h>

#define N_PTS 65536
#define BATCH 2
#define KNN   16
#define NBLK_S2 2048
#define NBLK_V1 512

typedef float float4n __attribute__((ext_vector_type(4)));

__device__ __forceinline__ int tri(int i, int j) { // i<=j, 7x7 upper triangle
    return i * 7 - (i * (i - 1)) / 2 + (j - i);
}

// ==== Fused: blocks [0,2048) = LEAN stats; blocks [2048,...) = feat broadcast ====
__global__ __launch_bounds__(256) void k_featstats(const float* __restrict__ feat,
                                                   float* __restrict__ out,
                                                   const float* __restrict__ coords,
                                                   const int* __restrict__ knn,
                                                   const float* __restrict__ dist,
                                                   float* __restrict__ partials) {
    int bid = blockIdx.x;
    if (bid < NBLK_S2) {
        int gid = bid * 256 + threadIdx.x;   // B*N*4 = 524288 threads
        int q  = gid & 3;
        int pp = gid >> 2;
        int b  = pp >> 16;
        const float* cp = coords + (size_t)pp * 3;
        float cx = cp[0], cy = cp[1], cz = cp[2];
        const float* cb = coords + (size_t)b * (N_PTS * 3);

        int4   ia = *(const int4*)  (knn  + ((size_t)pp << 4) + (q << 2));
        float4 da = *(const float4*)(dist + ((size_t)pp << 4) + (q << 2));
        int   idx[4] = {ia.x, ia.y, ia.z, ia.w};
        float dd[4]  = {da.x, da.y, da.z, da.w};

        float Gx = 0.f, Gy = 0.f, Gz = 0.f, D1 = 0.f, D2 = 0.f;
        float Sxx = 0.f, Sxy = 0.f, Sxz = 0.f, Syy = 0.f, Syz = 0.f, Szz = 0.f;
        float NDx = 0.f, NDy = 0.f, NDz = 0.f;
#pragma unroll
        for (int k = 0; k < 4; k++) {
            const float* qq = cb + (size_t)idx[k] * 3;
            float nx = qq[0], ny = qq[1], nz = qq[2], d = dd[k];
            Gx += nx; Gy += ny; Gz += nz; D1 += d; D2 += d * d;
            Sxx += nx * nx; Sxy += nx * ny; Sxz += nx * nz;
            Syy += ny * ny; Syz += ny * nz; Szz += nz * nz;
            NDx += nx * d; NDy += ny * d; NDz += nz * d;
        }

        __shared__ float red[4][35];
        int lane = threadIdx.x & 63, wid = threadIdx.x >> 6;
        int slot = 0;
#define RED1(expr) { float v_ = (expr); \
        v_ += __shfl_xor(v_, 32); v_ += __shfl_xor(v_, 16); \
        v_ += __shfl_xor(v_, 8);  v_ += __shfl_xor(v_, 4);  \
        v_ += __shfl_xor(v_, 2);  v_ += __shfl_xor(v_, 1);  \
        if (lane == 0) red[wid][slot] = v_; slot++; }
        RED1(4.f*cx) RED1(4.f*cy) RED1(4.f*cz) RED1(Gx) RED1(Gy) RED1(Gz) RED1(D1)
        RED1(4.f*cx*cx) RED1(4.f*cx*cy) RED1(4.f*cx*cz)
        RED1(cx*Gx) RED1(cx*Gy) RED1(cx*Gz) RED1(cx*D1)
        RED1(4.f*cy*cy) RED1(4.f*cy*cz)
        RED1(cy*Gx) RED1(cy*Gy) RED1(cy*Gz) RED1(cy*D1)
        RED1(4.f*cz*cz)
        RED1(cz*Gx) RED1(cz*Gy) RED1(cz*Gz) RED1(cz*D1)
        RED1(Sxx) RED1(Sxy) RED1(Sxz) RED1(NDx)
        RED1(Syy) RED1(Syz) RED1(NDy)
        RED1(Szz) RED1(NDz)
        RED1(D2)
#undef RED1
        __syncthreads();
        if (threadIdx.x < 35) {
            int i = threadIdx.x;
            partials[i * NBLK_S2 + bid] =
                (red[0][i] + red[1][i]) + (red[2][i] + red[3][i]);
        }
    } else {
        int gid = (bid - NBLK_S2) * 256 + threadIdx.x;
        int q4 = gid & 3;
        int r  = gid >> 2;
        float v = feat[r];
        int b = r >> 22;
        int f = (r >> 16) & 63;
        int n = r & 0xFFFF;
        size_t base = (((size_t)b * 128 + 64 + f) * N_PTS + n) * KNN + (q4 << 2);
        float4n vv = {v, v, v, v};
        __builtin_nontemporal_store(vv, reinterpret_cast<float4n*>(out + base));
    }
}

// ==== prep: 256-thread parallel partials reduce + BN fold ====
__global__ __launch_bounds__(256) void k_prep256(const float* __restrict__ W,
                                                 const float* __restrict__ bias,
                                                 const float* __restrict__ gamma,
                                                 const float* __restrict__ beta,
                                                 const float* __restrict__ partials,
                                                 float* __restrict__ w8) {
    __shared__ float red[4][35];
    __shared__ float sst[35];
    int t = threadIdx.x;
    float acc[35];
    const float* p0 = partials + t * 8;
#pragma unroll
    for (int i = 0; i < 35; i++) {
        const float* p = p0 + i * NBLK_S2;
        float4 a = *(const float4*)p;
        float4 c = *(const float4*)(p + 4);
        acc[i] = ((a.x + a.y) + (a.z + a.w)) + ((c.x + c.y) + (c.z + c.w));
    }
    int lane = t & 63, wid = t >> 6;
#pragma unroll
    for (int i = 0; i < 35; i++) {
        float v = acc[i];
#pragma unroll
        for (int off = 32; off; off >>= 1) v += __shfl_xor(v, off);
        if (lane == 0) red[wid][i] = v;
    }
    __syncthreads();
    if (t < 35) sst[t] = (red[0][t] + red[1][t]) + (red[2][t] + red[3][t]);
    __syncthreads();

    if (t >= 64) return;
    int o = t;
    const float invM = 1.0f / (float)((size_t)BATCH * N_PTS * KNN);
    float m[7];
#pragma unroll
    for (int j = 0; j < 7; j++) m[j] = sst[j] * invM;
    const float* Wo = W + o * 10;
    float wv[7];
    wv[0] = Wo[0] + Wo[6]; wv[1] = Wo[1] + Wo[7]; wv[2] = Wo[2] + Wo[8];
    wv[3] = Wo[3] - Wo[6]; wv[4] = Wo[4] - Wo[7]; wv[5] = Wo[5] - Wo[8];
    wv[6] = Wo[9];
    float mean = bias[o];
#pragma unroll
    for (int j = 0; j < 7; j++) mean += wv[j] * m[j];
    float var = 0.f;
#pragma unroll
    for (int i = 0; i < 7; i++) {
#pragma unroll
        for (int j = 0; j < 7; j++) {
            int a = i < j ? i : j, c = i < j ? j : i;
            float cov = sst[7 + tri(a, c)] * invM - m[i] * m[j];
            var += wv[i] * wv[j] * cov;
        }
    }
    float s = gamma[o] * rsqrtf(var + 1e-6f);
    float sh = beta[o] - mean * s;
#pragma unroll
    for (int j = 0; j < 7; j++) w8[o * 8 + j] = s * wv[j];
    w8[o * 8 + 7] = s * bias[o] + sh;
}

// ==== fallback stats (512 blocks) ====
__global__ __launch_bounds__(256) void k_stats_fb(const float* __restrict__ coords,
                                                  const int* __restrict__ knn,
                                                  const float* __restrict__ dist,
                                                  float* __restrict__ stats_atomic,
                                                  float* __restrict__ partials,
                                                  int use_part) {
    int gid = blockIdx.x * 256 + threadIdx.x;
    int b = gid >> 16;
    const float* cp = coords + (size_t)gid * 3;
    float cx = cp[0], cy = cp[1], cz = cp[2];
    const float* cb = coords + (size_t)b * (N_PTS * 3);
    const int* ip = knn + ((size_t)gid << 4);
    const float* dp = dist + ((size_t)gid << 4);

    float s[35];
#pragma unroll
    for (int i = 0; i < 35; i++) s[i] = 0.f;
    for (int k = 0; k < KNN; k++) {
        int idx = ip[k];
        const float* q = cb + (size_t)idx * 3;
        float v[7];
        v[0] = cx; v[1] = cy; v[2] = cz;
        v[3] = q[0]; v[4] = q[1]; v[5] = q[2];
        v[6] = dp[k];
        int t = 7;
#pragma unroll
        for (int i = 0; i < 7; i++) {
            s[i] += v[i];
#pragma unroll
            for (int j = i; j < 7; j++) { s[t] += v[i] * v[j]; t++; }
        }
    }
    __shared__ float red[4][35];
    int lane = threadIdx.x & 63;
    int wid  = threadIdx.x >> 6;
#pragma unroll
    for (int i = 0; i < 35; i++) {
        float v = s[i];
#pragma unroll
        for (int off = 32; off; off >>= 1) v += __shfl_xor(v, off);
        if (lane == 0) red[wid][i] = v;
    }
    __syncthreads();
    if (threadIdx.x < 35) {
        int i = threadIdx.x;
        float v = (red[0][i] + red[1][i]) + (red[2][i] + red[3][i]);
        if (use_part) partials[i * NBLK_V1 + blockIdx.x] = v;
        else          atomicAdd(&stats_atomic[i], v);
    }
}

// ==== fallback prep (64 threads) ====
__global__ __launch_bounds__(64) void k_prep_fb(const float* __restrict__ W,
                                                const float* __restrict__ bias,
                                                const float* __restrict__ gamma,
                                                const float* __restrict__ beta,
                                                const float* __restrict__ stats_atomic,
                                                const float* __restrict__ partials,
                                                int use_part,
                                                float* __restrict__ w8) {
    __shared__ float sst[35];
    int t = threadIdx.x;
    if (t < 35) {
        if (use_part) {
            const float* p = partials + t * NBLK_V1;
            float a0 = 0.f, a1 = 0.f, a2 = 0.f, a3 = 0.f;
            for (int j = 0; j < NBLK_V1; j += 4) {
                a0 += p[j]; a1 += p[j + 1]; a2 += p[j + 2]; a3 += p[j + 3];
            }
            sst[t] = (a0 + a1) + (a2 + a3);
        } else {
            sst[t] = stats_atomic[t];
        }
    }
    __syncthreads();
    int o = t;
    const float invM = 1.0f / (float)((size_t)BATCH * N_PTS * KNN);
    float m[7];
#pragma unroll
    for (int j = 0; j < 7; j++) m[j] = sst[j] * invM;
    const float* Wo = W + o * 10;
    float wv[7];
    wv[0] = Wo[0] + Wo[6]; wv[1] = Wo[1] + Wo[7]; wv[2] = Wo[2] + Wo[8];
    wv[3] = Wo[3] - Wo[6]; wv[4] = Wo[4] - Wo[7]; wv[5] = Wo[5] - Wo[8];
    wv[6] = Wo[9];
    float mean = bias[o];
#pragma unroll
    for (int j = 0; j < 7; j++) mean += wv[j] * m[j];
    float var = 0.f;
#pragma unroll
    for (int i = 0; i < 7; i++) {
#pragma unroll
        for (int j = 0; j < 7; j++) {
            int a = i < j ? i : j, c = i < j ? j : i;
            float cov = sst[7 + tri(a, c)] * invM - m[i] * m[j];
            var += wv[i] * wv[j] * cov;
        }
    }
    float s = gamma[o] * rsqrtf(var + 1e-6f);
    float sh = beta[o] - mean * s;
#pragma unroll
    for (int j = 0; j < 7; j++) w8[o * 8 + j] = s * wv[j];
    w8[o * 8 + 7] = s * bias[o] + sh;
}

// ==== fallback standalone feat broadcast ====
__global__ __launch_bounds__(256) void k_feat(const float* __restrict__ feat,
                                              float* __restrict__ out) {
    int gid = blockIdx.x * 256 + threadIdx.x;
    int q4 = gid & 3;
    int r  = gid >> 2;
    float v = feat[r];
    int b = r >> 22;
    int f = (r >> 16) & 63;
    int n = r & 0xFFFF;
    size_t base = (((size_t)b * 128 + 64 + f) * N_PTS + n) * KNN + (q4 << 2);
    float4n vv = {v, v, v, v};
    __builtin_nontemporal_store(vv, reinterpret_cast<float4n*>(out + base));
}

// ==== Pass 2 v2: LDS-tiled x channels. Block = 128 points; per (wave,channel)
// the store loop advances n -> 8x 1KB sequential NT stores (low address bits
// sweep -> HBM channels balanced, unlike the 4MiB c-hop of the old k_x).
// LDS tile is lane-linear: every ds_read_b128 is a contiguous 1KB wave read. ====
__global__ __launch_bounds__(256) void k_x2(const float* __restrict__ coords,
                                            const int* __restrict__ knn,
                                            const float* __restrict__ dist,
                                            const float* __restrict__ w8g,
                                            float* __restrict__ out) {
    __shared__ float4n sp2[2048];   // [(j*4+kk)*64 + lane] = {nx,ny,nz,d}  (32KB)
    __shared__ float4n cxy[128];    // {cx,cy,cz,-}                          (2KB)
    __shared__ float   w8[512];     //                                       (2KB)

    int tid = threadIdx.x;
    int pp0 = blockIdx.x * 128;          // 128 consecutive (b*N+n); b constant in block
    int b   = pp0 >> 16;
    const float* cb = coords + (size_t)b * (N_PTS * 3);

    for (int i = tid; i < 512; i += 256) w8[i] = w8g[i];
    if (tid < 128) {
        const float* cp = coords + (size_t)(pp0 + tid) * 3;
        float4n c = {cp[0], cp[1], cp[2], 0.f};
        cxy[tid] = c;
    }
#pragma unroll
    for (int s = 0; s < 2; s++) {
        int Q  = tid + s * 256;          // 0..511 quads
        int pt = Q >> 2, q = Q & 3;
        int pp = pp0 + pt;
        int4   ia = *(const int4*)  (knn  + ((size_t)pp << 4) + (q << 2));
        float4 da = *(const float4*)(dist + ((size_t)pp << 4) + (q << 2));
        int   idx[4] = {ia.x, ia.y, ia.z, ia.w};
        float dd[4]  = {da.x, da.y, da.z, da.w};
        int base = ((pt >> 4) * 4) * 64 + (pt & 15) * 4 + q;  // + kk*64
#pragma unroll
        for (int kk = 0; kk < 4; kk++) {
            const float* qq = cb + (size_t)idx[kk] * 3;
            float4n v = {qq[0], qq[1], qq[2], dd[kk]};
            sp2[base + kk * 64] = v;
        }
    }
    __syncthreads();

    int lane = tid & 63, wv = tid >> 6;
    int q = lane & 3, ptl = lane >> 2;
    int n0 = pp0 & 0xFFFF;
    const size_t CS = (size_t)N_PTS * KNN;          // channel stride (floats)
    float* outp = out + ((size_t)b * 128) * CS + (size_t)n0 * KNN;

    for (int ci = 0; ci < 16; ci++) {
        int c = wv * 16 + ci;
        float4 wa = *reinterpret_cast<const float4*>(&w8[c << 3]);
        float4 wb = *reinterpret_cast<const float4*>(&w8[(c << 3) + 4]);
        float* oc = outp + (size_t)c * CS;
#pragma unroll
        for (int j = 0; j < 8; j++) {
            int pt = j * 16 + ptl;
            float4n cc = cxy[pt];
            float s0 = fmaf(cc.x, wa.x, fmaf(cc.y, wa.y, fmaf(cc.z, wa.z, wb.w)));
            float x[4];
#pragma unroll
            for (int kk = 0; kk < 4; kk++) {
                float4n v = sp2[(j * 4 + kk) * 64 + lane];
                x[kk] = fmaxf(fmaf(v.w, wb.z, fmaf(v.z, wb.y,
                              fmaf(v.y, wb.x, fmaf(v.x, wa.w, s0)))), 0.f);
            }
            float4n o = {x[0], x[1], x[2], x[3]};
            __builtin_nontemporal_store(o,
                reinterpret_cast<float4n*>(oc + (pt << 4) + (q << 2)));
        }
    }
}

extern "C" void kernel_launch(void* const* d_in, const int* in_sizes, int n_in,
                              void* d_out, int out_size, void* d_ws, size_t ws_size,
                              hipStream_t stream) {
    const float* coords   = (const float*)d_in[0];
    const float* features = (const float*)d_in[1];
    const int*   knn      = (const int*)d_in[2];
    const float* dist     = (const float*)d_in[3];
    const float* W        = (const float*)d_in[4];
    const float* bias     = (const float*)d_in[5];
    const float* gamma    = (const float*)d_in[6];
    const float* beta     = (const float*)d_in[7];
    float* out            = (float*)d_out;

    float* stats    = (float*)d_ws;
    float* w8       = stats + 64;
    float* partials = w8 + 512;
    size_t need2 = (64 + 512 + 35 * NBLK_S2) * sizeof(float);
    size_t need1 = (64 + 512 + 35 * NBLK_V1) * sizeof(float);

    if (ws_size >= need2) {
        k_featstats<<<NBLK_S2 + 131072, 256, 0, stream>>>(features, out, coords, knn, dist,
                                                          partials);
        k_prep256<<<1, 256, 0, stream>>>(W, bias, gamma, beta, partials, w8);
    } else {
        int use_part = (ws_size >= need1) ? 1 : 0;
        if (!use_part)
            (void)hipMemsetAsync(d_ws, 0, 64 * sizeof(float), stream);
        k_stats_fb<<<NBLK_V1, 256, 0, stream>>>(coords, knn, dist, stats, partials, use_part);
        k_prep_fb<<<1, 64, 0, stream>>>(W, bias, gamma, beta, stats, partials, use_part, w8);
        k_feat<<<131072, 256, 0, stream>>>(features, out);
    }
    k_x2<<<(BATCH * N_PTS) / 128, 256, 0, stream>>>(coords, knn, dist, w8, out);
}